// Round 1
// 80.481 us; speedup vs baseline: 1.0069x; 1.0069x over previous
//
#include <hip/hip_runtime.h>

typedef __attribute__((ext_vector_type(4)))  short bf16x4;   // 4 bf16 = 2 VGPRs
typedef __attribute__((ext_vector_type(16))) float f32x16;   // MFMA 32x32 C/D

#define TPB    256
#define NPTS   8192
#define NB     4
#define TOTPTS (NB * NPTS)        // 32768
#define XWAVE  64                 // x per wave (2 B-frags)
#define XBLK   (4 * XWAVE)        // 256 x per block
#define YTILE  1024               // y per block
#define NTILES (YTILE / 32)       // 32 MFMA tiles
#define GXB    (NPTS / XBLK)      // 32
#define GYB    (NPTS / YTILE)     // 8 y-chunks
#define NSLICE (2 * NB)           // 8 (dir,batch) slices per chunk
#define WS2_FLOATS ((size_t)GYB * NSLICE * NPTS)  // 512K floats = 2 MB
#define NPARTIAL ((2 * TOTPTS) / 64)   // 1024

// ---------------------------------------------------------------------------
// R21: occupancy attack via accumulator collapse.
// Insight: all 16 regs of one MFMA result are different y-rows of the SAME
// x-column -> they all feed one min-reduction. rm[2][16] (32 VGPRs of running
// mins) was pure register waste; an immediate v_min3 tree (8 ops/MFMA, same
// VALU op count as before since each d^2 is touched exactly once) collapses
// accumulator state to rm[2] (2 VGPRs). Goal: natural VGPR allocation <=128
// -> 4 waves/SIMD (was 2) WITHOUT a launch_bounds cap (R10/R14: caps push rm
// into AGPRs -> accvgpr churn / corruption). Bit-exact vs R18 (min is
// order-independent): absmax must remain 0.01171875.
// Prior exhausted levers (kept from R18's post-mortem):
//   ILP pipelines: R12 device-abort, R20 hazard corruption.
//   TLP retune (XWAVE=32, lb(256,4)): R14/R15 deterministic corruption.
//   Tile scaling: R13 neutral. Kernel fusion: R4/R19 fence/coherence tax.
//   Packed fp32: R5/R6 no throughput on gfx950.
// Structure: K=8 mfma_f32_32x32x8bf16_1k (8 K-slots: y compensated hi/lo +
// hy split; x bf16-rounded — finalize uses identically-rounded hx so
// d = |xh - y|, err ~0.01 < 0.036 threshold):
//   A (y, M) k: [yh0,yl0, yh1,yl1 | yh2,yl2, hyh,hyl]
//   B (x, N) k: [-xh0,-xh0, -xh1,-xh1 | -xh2,-xh2, 1,1]
// Combine: asm v_min3_f32 tree (R10: plain fminf -> accvgpr churn; VOP3
// cannot source AGPRs). unroll 2 (R9: full unroll hoists ds_reads -> spill).
// launch_bounds(256,1): no VGPR cap, allocator keeps arch-VGPR form.
// Disjoint-slice plain stores, no atomics/init (R16). 3 launches: kernel
// boundary is the only cheap cross-XCD flush (R14/R19).
// Budget: ~40us harness 0xAA ws-fill (sunk) + nnmin (target ~17) +
// finalize/scalar/gaps ~13.
// ---------------------------------------------------------------------------

__device__ __forceinline__ short bfr(float f) {       // fp32->bf16 RNE
    unsigned u = __float_as_uint(f);
    return (short)((u + 0x7FFFu + ((u >> 16) & 1u)) >> 16);
}
__device__ __forceinline__ float bf2f(short s) {
    return __uint_as_float(((unsigned)(unsigned short)s) << 16);
}
__device__ __forceinline__ float min3f(float a, float b, float c) {
    float d;
    asm("v_min3_f32 %0, %1, %2, %3" : "=v"(d) : "v"(a), "v"(b), "v"(c));
    return d;
}

// grid = (GXB, GYB, 2*NB) = (32, 8, 8) = 2048 blocks, 4 waves each.
// Wave owns 64 x (2 B-frags); block stages YTILE=1024 y as A-frags in LDS.
__global__ void __launch_bounds__(TPB, 1) nnmin_mfma(
        const float* __restrict__ T, const float* __restrict__ P,
        float* __restrict__ ws2)
{
    __shared__ bf16x4 sA[NTILES * 64];   // A-fragments, 16 KB

    const int z   = blockIdx.z;
    const int dir = z >> 2;
    const int b   = z & 3;
    const float* Xb = (dir ? P : T) + (size_t)b * NPTS * 3;
    const float* Yb = (dir ? T : P) + (size_t)b * NPTS * 3;
    const int t     = threadIdx.x;
    const int l     = t & 63;          // lane
    const int w     = t >> 6;          // wave id (0..3)
    const int ybase = blockIdx.y * YTILE;
    const int xw    = blockIdx.x * XBLK + w * XWAVE;   // wave's 64 x

    // ---- stage A-fragments: y compensated hi/lo, hy split ----
    for (int p = t; p < YTILE; p += TPB) {
        const float* yp = Yb + (size_t)(ybase + p) * 3;
        float y0 = yp[0], y1 = yp[1], y2 = yp[2];
        short yh0 = bfr(y0); short yl0 = bfr(y0 - bf2f(yh0));
        short yh1 = bfr(y1); short yl1 = bfr(y1 - bf2f(yh1));
        short yh2 = bfr(y2); short yl2 = bfr(y2 - bf2f(yh2));
        float hy  = 0.5f * (y0 * y0 + y1 * y1 + y2 * y2);
        short hyh = bfr(hy); short hyl = bfr(hy - bf2f(hyh));
        int tile = p >> 5, m = p & 31;
        bf16x4 e0 = {yh0, yl0, yh1, yl1};   // k = 0..3  (lanes < 32)
        bf16x4 e1 = {yh2, yl2, hyh, hyl};   // k = 4..7  (lanes >= 32)
        sA[tile * 64 + m]      = e0;
        sA[tile * 64 + 32 + m] = e1;
    }

    // ---- build the wave's 2 B-fragments: x bf16-rounded, negated ----
    const int   kh  = l >> 5;          // which K-half this lane supplies
    const short ONE = 0x3F80;          // bf16(1.0)
    bf16x4 B[2];
#pragma unroll
    for (int f = 0; f < 2; ++f) {
        const float* xp = Xb + (size_t)(xw + f * 32 + (l & 31)) * 3;
        short h0 = bfr(-xp[0]);        // RNE is sign-symmetric
        short h1 = bfr(-xp[1]);
        short h2 = bfr(-xp[2]);
        bf16x4 e;
        if (kh == 0) e = (bf16x4){h0, h0, h1, h1};
        else         e = (bf16x4){h2, h2, ONE, ONE};
        B[f] = e;
    }
    __syncthreads();

    // ---- main loop: 2 ds_read_b64 + 4 MFMA(K=8) + 32 asm min3 ----
    f32x16 zero = {0.f};               // loop-invariant C input
    float rm[2];                       // running mins — 2 VGPRs (was 32)
    rm[0] = 3.0e38f;
    rm[1] = 3.0e38f;

#pragma unroll 2                       // bound A-frag hoisting (R9 spilled)
    for (int tl = 0; tl < NTILES; tl += 2) {
        bf16x4 Aa = sA[(tl + 0) * 64 + l];
        bf16x4 Ab = sA[(tl + 1) * 64 + l];
#pragma unroll
        for (int f = 0; f < 2; ++f) {
            f32x16 da = __builtin_amdgcn_mfma_f32_32x32x8bf16_1k(Aa, B[f], zero, 0, 0, 0);
            f32x16 db = __builtin_amdgcn_mfma_f32_32x32x8bf16_1k(Ab, B[f], zero, 0, 0, 0);
            // 16-op min3 tree: same VALU op count as before, 30 fewer VGPRs.
            float u0 = min3f(da[0],  da[1],  da[2]);
            float u1 = min3f(da[3],  da[4],  da[5]);
            float u2 = min3f(da[6],  da[7],  da[8]);
            float u3 = min3f(da[9],  da[10], da[11]);
            float u4 = min3f(da[12], da[13], da[14]);
            float w0 = min3f(u0, u1, u2);
            float w1 = min3f(u3, u4, da[15]);
            float v0 = min3f(db[0],  db[1],  db[2]);
            float v1 = min3f(db[3],  db[4],  db[5]);
            float v2 = min3f(db[6],  db[7],  db[8]);
            float v3 = min3f(db[9],  db[10], db[11]);
            float v4 = min3f(db[12], db[13], db[14]);
            float w2 = min3f(v0, v1, v2);
            float w3 = min3f(v3, v4, db[15]);
            float x0 = min3f(w0, w1, w2);
            asm("v_min3_f32 %0, %0, %1, %2"
                : "+v"(rm[f]) : "v"(x0), "v"(w3));
        }
    }

    // ---- epilogue: cross-half min + plain store to own slice ----
    float* o = ws2 + ((size_t)blockIdx.y * NSLICE + z) * NPTS;
#pragma unroll
    for (int f = 0; f < 2; ++f) {
        float v = fminf(rm[f], __shfl_xor(rm[f], 32, 64));  // rows split across halves
        if (l < 32) o[xw + f * 32 + l] = v;    // disjoint: no atomics, no init
    }
}

// Min-reduce 8 chunk slices, add hx(ROUNDED x), sqrt; mins_seeds; wave sums.
__global__ void __launch_bounds__(TPB) finalize_kernel(
        const float* __restrict__ ws2,
        const float* __restrict__ T, const float* __restrict__ P,
        float* __restrict__ out, float* __restrict__ partials)
{
    int i   = blockIdx.x * TPB + threadIdx.x;   // 0 .. 2*TOTPTS-1
    int dir = (i >= TOTPTS) ? 1 : 0;            // uniform per block
    int idx = i - dir * TOTPTS;
    int b   = idx >> 13;
    int x   = idx & (NPTS - 1);

    const float* p0 = ws2 + (size_t)(dir * 4 + b) * NPTS + x;
    float m = 3.0e38f;
#pragma unroll
    for (int c = 0; c < GYB; ++c)               // 8 loads from 2MB (L2)
        m = fminf(m, p0[(size_t)c * NSLICE * NPTS]);

    // hx from the SAME bf16 rounding the MFMA B-side used: d = |xh - y|
    const float* xp = (dir ? P : T) + ((size_t)b * NPTS + x) * 3;
    float a0 = bf2f(bfr(xp[0]));
    float a1 = bf2f(bfr(xp[1]));
    float a2 = bf2f(bfr(xp[2]));
    float hx = 0.5f * (a0 * a0 + a1 * a1 + a2 * a2);
    float d  = sqrtf(fmaxf(2.0f * (hx + m), 0.0f));
    if (dir) out[1 + idx] = d;                  // mins_seeds

#pragma unroll
    for (int off = 32; off > 0; off >>= 1)
        d += __shfl_down(d, off, 64);
    if ((threadIdx.x & 63) == 0) partials[i >> 6] = d;
}

// Single-wave final reduction (separate launch: kernel boundary is the only
// cheap reliable cross-XCD flush — R14/R19 lessons).
__global__ void scalar_kernel(const float* __restrict__ partials,
                              float* __restrict__ out) {
    int t = threadIdx.x;                        // 64 threads
    float s = 0.0f;
#pragma unroll
    for (int k = 0; k < NPARTIAL / 64; ++k)
        s += partials[t + 64 * k];              // coalesced (was stride-64B)
#pragma unroll
    for (int off = 32; off > 0; off >>= 1)
        s += __shfl_down(s, off, 64);
    if (t == 0) out[0] = s * (1.0f / (float)TOTPTS);
}

extern "C" void kernel_launch(void* const* d_in, const int* in_sizes, int n_in,
                              void* d_out, int out_size, void* d_ws, size_t ws_size,
                              hipStream_t stream) {
    const float* truep = (const float*)d_in[0];   // [4, 8192, 3] fp32
    const float* predp = (const float*)d_in[1];   // [4, 8192, 3] fp32
    float* out = (float*)d_out;                   // [1 + 32768] fp32

    float* ws2      = (float*)d_ws;               // 2 MB chunk mins (no init)
    float* partials = ws2 + WS2_FLOATS;           // 1024 floats (write-first)

    dim3 grid(GXB, GYB, 2 * NB);                  // (32, 8, 8) = 2048 blocks
    nnmin_mfma<<<grid, TPB, 0, stream>>>(truep, predp, ws2);

    finalize_kernel<<<(2 * TOTPTS) / TPB, TPB, 0, stream>>>(
        ws2, truep, predp, out, partials);
    scalar_kernel<<<1, 64, 0, stream>>>(partials, out);
}